// Round 1
// baseline (441.154 us; speedup 1.0000x reference)
//
#include <hip/hip_runtime.h>
#include <math.h>

#define HID 1024
#define VOC 50257
#define MLEN 12

__device__ __forceinline__ float wave_reduce_sum(float v) {
    for (int off = 32; off > 0; off >>= 1)
        v += __shfl_down(v, off, 64);
    return v;
}

// K1: embedding lookup + attention softmax + attn_applied; writes xin = [embedded, attn_applied]
__global__ __launch_bounds__(256) void k1_embed_attn(
    const int* __restrict__ tok_p, const float* __restrict__ h0,
    const float* __restrict__ enc, const float* __restrict__ emb,
    const float* __restrict__ attn_W, const float* __restrict__ attn_b,
    float* __restrict__ ws_xin, float* __restrict__ out_attnw)
{
    __shared__ float lds_logits[MLEN];
    __shared__ float lds_w[MLEN];
    const int t = threadIdx.x;
    const int wid = t >> 6, lane = t & 63;
    const int tok = tok_p[0];  // int64 little-endian low word == value (tok < 50257)
    const float4* emb4 = (const float4*)(emb + (size_t)tok * HID);
    const float4* h04  = (const float4*)h0;
    const float4* aW4  = (const float4*)attn_W;

    // 12 attention logits, one wave per logit (waves cycle)
    for (int l = wid; l < MLEN; l += 4) {
        float s = 0.f;
        for (int k = 0; k < 8; ++k) {
            int idx = k * 64 + lane;                      // 0..511 float4s of the 2048-vec
            float4 v = (idx < 256) ? emb4[idx] : h04[idx - 256];
            float4 w = aW4[l * 512 + idx];
            s += v.x * w.x + v.y * w.y + v.z * w.z + v.w * w.w;
        }
        s = wave_reduce_sum(s);
        if (lane == 0) lds_logits[l] = s + attn_b[l];
    }
    __syncthreads();
    if (t == 0) {
        float m = -1e30f;
        for (int l = 0; l < MLEN; ++l) m = fmaxf(m, lds_logits[l]);
        float ssum = 0.f;
        for (int l = 0; l < MLEN; ++l) { float e = expf(lds_logits[l] - m); lds_w[l] = e; ssum += e; }
        float inv = 1.f / ssum;
        for (int l = 0; l < MLEN; ++l) { lds_w[l] *= inv; out_attnw[l] = lds_w[l]; }
    }
    __syncthreads();

    // attn_applied (1024) + copy embedded; one float4 per thread
    const float4* enc4 = (const float4*)enc;
    float4 e = emb4[t];
    float4 acc = make_float4(0.f, 0.f, 0.f, 0.f);
    for (int l = 0; l < MLEN; ++l) {
        float wl = lds_w[l];
        float4 v = enc4[l * 256 + t];
        acc.x += wl * v.x; acc.y += wl * v.y; acc.z += wl * v.z; acc.w += wl * v.w;
    }
    float4* xin4 = (float4*)ws_xin;
    xin4[t] = e;
    xin4[256 + t] = acc;
}

// K2: x = relu(comb_W @ xin + comb_b); 1024 rows, dot length 2048; wave per row
__global__ __launch_bounds__(256) void k2_comb(
    const float* __restrict__ ws_xin, const float* __restrict__ comb_W,
    const float* __restrict__ comb_b, float* __restrict__ ws_x)
{
    const int wid = threadIdx.x >> 6, lane = threadIdx.x & 63;
    const int row = blockIdx.x * 4 + wid;                 // 0..1023
    const float4* W4 = (const float4*)(comb_W + (size_t)row * 2048);
    const float4* v4 = (const float4*)ws_xin;
    float s = 0.f;
    for (int k = 0; k < 8; ++k) {
        int idx = k * 64 + lane;
        float4 w = W4[idx], v = v4[idx];
        s += w.x * v.x + w.y * v.y + w.z * v.z + w.w * v.w;
    }
    s = wave_reduce_sum(s);
    if (lane == 0) ws_x[row] = fmaxf(s + comb_b[row], 0.f);
}

// K3: gates = W_ih @ x + b_ih + W_hh @ h0 + b_hh; 4096 rows, two dots of length 1024
__global__ __launch_bounds__(256) void k3_gates(
    const float* __restrict__ ws_x, const float* __restrict__ h0,
    const float* __restrict__ W_ih, const float* __restrict__ W_hh,
    const float* __restrict__ b_ih, const float* __restrict__ b_hh,
    float* __restrict__ ws_gates)
{
    const int wid = threadIdx.x >> 6, lane = threadIdx.x & 63;
    const int row = blockIdx.x * 4 + wid;                 // 0..4095
    const float4* Wi4 = (const float4*)(W_ih + (size_t)row * HID);
    const float4* Wh4 = (const float4*)(W_hh + (size_t)row * HID);
    const float4* x4  = (const float4*)ws_x;
    const float4* h4  = (const float4*)h0;
    float s = 0.f;
    for (int k = 0; k < 4; ++k) {
        int idx = k * 64 + lane;
        float4 wi = Wi4[idx], xv = x4[idx];
        float4 wh = Wh4[idx], hv = h4[idx];
        s += wi.x * xv.x + wi.y * xv.y + wi.z * xv.z + wi.w * xv.w;
        s += wh.x * hv.x + wh.y * hv.y + wh.z * hv.z + wh.w * hv.w;
    }
    s = wave_reduce_sum(s);
    if (lane == 0) ws_gates[row] = s + b_ih[row] + b_hh[row];
}

// K4: LSTM cell elementwise (PyTorch gate order i,f,g,o)
__global__ __launch_bounds__(1024) void k4_lstm(
    const float* __restrict__ ws_gates, const float* __restrict__ c0,
    float* __restrict__ out_h, float* __restrict__ out_c, float* __restrict__ ws_h)
{
    const int t = threadIdx.x;
    float ig = ws_gates[t];
    float fg = ws_gates[HID + t];
    float gg = ws_gates[2 * HID + t];
    float og = ws_gates[3 * HID + t];
    float i = 1.f / (1.f + expf(-ig));
    float f = 1.f / (1.f + expf(-fg));
    float o = 1.f / (1.f + expf(-og));
    float g = tanhf(gg);
    float c = f * c0[t] + i * g;
    float h = o * tanhf(c);
    out_c[t] = c;
    out_h[t] = h;
    ws_h[t] = h;   // 16B-aligned copy for K5's float4 reads
}

// K5: logits = out_W @ h + out_b; 50257 rows; wave per row (raw logits into out)
__global__ __launch_bounds__(256) void k5_logits(
    const float* __restrict__ ws_h, const float* __restrict__ out_W,
    const float* __restrict__ out_b, float* __restrict__ out_logp)
{
    const int wid = threadIdx.x >> 6, lane = threadIdx.x & 63;
    const int row = blockIdx.x * 4 + wid;
    if (row >= VOC) return;
    const float4* W4 = (const float4*)(out_W + (size_t)row * HID);
    const float4* h4 = (const float4*)ws_h;
    float s = 0.f;
    for (int k = 0; k < 4; ++k) {
        int idx = k * 64 + lane;
        float4 w = W4[idx], h = h4[idx];
        s += w.x * h.x + w.y * h.y + w.z * h.z + w.w * h.w;
    }
    s = wave_reduce_sum(s);
    if (lane == 0) out_logp[row] = s + out_b[row];
}

// K6: single-block log-sum-exp over the 50257 logits
__global__ __launch_bounds__(1024) void k6_lse(
    const float* __restrict__ logits, float* __restrict__ ws_lse)
{
    __shared__ float red[16];
    __shared__ float red2[16];
    const int t = threadIdx.x;
    const int wid = t >> 6, lane = t & 63;
    float m = -1e30f;
    for (int i = t; i < VOC; i += 1024) m = fmaxf(m, logits[i]);
    for (int off = 32; off > 0; off >>= 1) m = fmaxf(m, __shfl_xor(m, off, 64));
    if (lane == 0) red[wid] = m;
    __syncthreads();
    if (t == 0) {
        float mm = red[0];
        for (int w = 1; w < 16; ++w) mm = fmaxf(mm, red[w]);
        red[0] = mm;
    }
    __syncthreads();
    m = red[0];
    float s = 0.f;
    for (int i = t; i < VOC; i += 1024) s += expf(logits[i] - m);
    s = wave_reduce_sum(s);
    if (lane == 0) red2[wid] = s;
    __syncthreads();
    if (t == 0) {
        float ss = 0.f;
        for (int w = 0; w < 16; ++w) ss += red2[w];
        ws_lse[0] = m + logf(ss);
    }
}

// K7: logp = logits - lse (in place)
__global__ __launch_bounds__(256) void k7_sub(
    float* __restrict__ out_logp, const float* __restrict__ ws_lse)
{
    const int i = blockIdx.x * 256 + threadIdx.x;
    if (i < VOC) out_logp[i] -= ws_lse[0];
}

extern "C" void kernel_launch(void* const* d_in, const int* in_sizes, int n_in,
                              void* d_out, int out_size, void* d_ws, size_t ws_size,
                              hipStream_t stream) {
    const int*   tok      = (const int*)d_in[0];
    const float* h_hidden = (const float*)d_in[1];
    const float* c_hidden = (const float*)d_in[2];
    const float* enc      = (const float*)d_in[3];
    const float* emb      = (const float*)d_in[4];
    const float* attn_W   = (const float*)d_in[5];
    const float* attn_b   = (const float*)d_in[6];
    const float* comb_W   = (const float*)d_in[7];
    const float* comb_b   = (const float*)d_in[8];
    const float* W_ih     = (const float*)d_in[9];
    const float* W_hh     = (const float*)d_in[10];
    const float* b_ih     = (const float*)d_in[11];
    const float* b_hh     = (const float*)d_in[12];
    const float* out_W    = (const float*)d_in[13];
    const float* out_b    = (const float*)d_in[14];

    float* out       = (float*)d_out;
    float* out_logp  = out;                       // [50257]
    float* out_h     = out + VOC;                 // [1024]
    float* out_c     = out + VOC + HID;           // [1024]
    float* out_attnw = out + VOC + 2 * HID;       // [12]

    float* ws       = (float*)d_ws;
    float* ws_xin   = ws;            // 2048 floats
    float* ws_x     = ws + 2048;     // 1024
    float* ws_gates = ws + 3072;     // 4096
    float* ws_h     = ws + 7168;     // 1024 (aligned copy of h_new)
    float* ws_lse   = ws + 8192;     // 1

    k1_embed_attn<<<1, 256, 0, stream>>>(tok, h_hidden, enc, emb, attn_W, attn_b,
                                         ws_xin, out_attnw);
    k2_comb<<<HID / 4, 256, 0, stream>>>(ws_xin, comb_W, comb_b, ws_x);
    k3_gates<<<4 * HID / 4, 256, 0, stream>>>(ws_x, h_hidden, W_ih, W_hh, b_ih, b_hh, ws_gates);
    k4_lstm<<<1, 1024, 0, stream>>>(ws_gates, c_hidden, out_h, out_c, ws_h);
    k5_logits<<<(VOC + 3) / 4, 256, 0, stream>>>(ws_h, out_W, out_b, out_logp);
    k6_lse<<<1, 1024, 0, stream>>>(out_logp, ws_lse);
    k7_sub<<<(VOC + 255) / 256, 256, 0, stream>>>(out_logp, ws_lse);
}